// Round 5
// baseline (905.962 us; speedup 1.0000x reference)
//
#include <hip/hip_runtime.h>
#include <hip/hip_bf16.h>
#include <cstdint>
#include <cstddef>

#define L      2048
#define IN_DIM 256
#define HID    13
#define G      52            // 4*HID
#define VOCAB  50257
#define PRED_N ((size_t)L * VOCAB)
#define L2E    1.4426950408889634f
#define NTX    99            // x-tiles of 512 cols (99*512 >= 50257)
#define NTY    16            // y-tiles of 128 rows
#define NTILE  (NTX * NTY)   // 1584
#define TILE_SPLIT (NTILE / 2)

static __device__ __forceinline__ float fexp2(float x) { return __builtin_amdgcn_exp2f(x); }
static __device__ __forceinline__ float frcp(float x) { return __builtin_amdgcn_rcpf(x); }
static __device__ __forceinline__ float sigm(float z) { return 1.f - frcp(fexp2(z * L2E) + 1.f); }
static __device__ __forceinline__ float tanh_(float z) { return 1.f - 2.f * frcp(fexp2(z * (2.f * L2E)) + 1.f); }

#define ROTF(h, j) __int_as_float(__builtin_amdgcn_update_dpp(__float_as_int(h), __float_as_int(h), 0x120 + (j), 0xF, 0xF, false))

// ---------------------------------------------------------------------------
// Kernel 1: embedding gather (-> d_out embs section, f32) + u0 = msc*(Wih0@emb+b0)
// padded layout [dir][L][64]; grid = L blocks, 128 threads
// ---------------------------------------------------------------------------
__global__ void k_emb_u0(const int* __restrict__ x, const float* __restrict__ embW,
                         const float* __restrict__ Wih0, const float* __restrict__ b0,
                         float* __restrict__ out_embs, float* __restrict__ u0)
{
    __shared__ float se[IN_DIM];
    int t = blockIdx.x;
    int tid = threadIdx.x;            // 128
    int rowx = x[t];
    float2 e = ((const float2*)(embW + (size_t)rowx * IN_DIM))[tid];
    se[2 * tid]     = e.x;
    se[2 * tid + 1] = e.y;
    ((float2*)(out_embs + (size_t)t * IN_DIM))[tid] = e;
    __syncthreads();
    if (tid < 2 * G) {
        int dirg = tid / G, g = tid % G;
        int gate = g / HID, row = g % HID;
        float msc = (gate == 2) ? 2.f * L2E : L2E;
        float acc = b0[dirg * G + g];
        const float* w = Wih0 + (size_t)(dirg * G + g) * IN_DIM;
        #pragma unroll 8
        for (int k = 0; k < IN_DIM; ++k)
            acc = fmaf(w[k], se[k], acc);
        u0[((size_t)dirg * L + t) * 64 + gate * 16 + row] = msc * acc;
    } else {
        int p = tid - 2 * G;          // 0..23 -> zero the 2*12 pad slots
        int dirp = p / 12, pp = p % 12;
        int gate = pp / 3, row = HID + pp % 3;
        u0[((size_t)dirp * L + t) * 64 + gate * 16 + row] = 0.f;
    }
}

// ---------------------------------------------------------------------------
// Kernel 2: decoder rows 1..L-1 (zero-state cells, parallel). dec[i][j], j<26
// ---------------------------------------------------------------------------
__global__ void k_rest(const int* __restrict__ x, const float* __restrict__ dWih,
                       const float* __restrict__ db, float* __restrict__ dec)
{
    int idx = blockIdx.x * blockDim.x + threadIdx.x;
    if (idx >= (L - 1) * 2 * HID) return;
    int i = idx / (2 * HID) + 1;
    int j = idx % (2 * HID);
    int dir = j / HID, jj = j % HID;
    float v = (float)x[i - 1];
    int base = dir * G;
    float zi = fmaf(dWih[base + jj],           v, db[base + jj]);
    float zg = fmaf(dWih[base + 2 * HID + jj], v, db[base + 2 * HID + jj]);
    float zo = fmaf(dWih[base + 3 * HID + jj], v, db[base + 3 * HID + jj]);
    float c2 = sigm(zi) * tanh_(zg);
    dec[(size_t)i * (2 * HID) + j] = sigm(zo) * tanh_(c2);
}

// ---------------------------------------------------------------------------
// Kernel 3/5: blocks 0,1 = one LSTM direction each (1 wave). All-lane redundant
// cell update (role-select after 3 permlane swaps) -> h replicated per 16-row
// -> matvec via 15 independent DPP row_ror rotations, no readlane/SGPR on chain.
// blocks >=2 = output-GEMM tiles (rows 1..L-1), hidden under the recurrence.
// ---------------------------------------------------------------------------
__global__ void __launch_bounds__(256) k_phase(
    const float* __restrict__ u, const float* __restrict__ Whh,
    float* __restrict__ out0, float* __restrict__ finh, float* __restrict__ finc,
    int chain_base, int do_out0,
    const float* __restrict__ dec, const float* __restrict__ outW,
    const float* __restrict__ outb, float* __restrict__ preds, int tile_base)
{
    __shared__ float sd[128][28];
    int bid = blockIdx.x;
    int tid = threadIdx.x;
    if (bid >= 2) {
        // ---- output-GEMM tile ----
        __builtin_amdgcn_s_setprio(0);
        int tile = bid - 2 + tile_base;
        int ix = tile % NTX, iy = tile / NTX;
        int nbase = ix * 512, i0 = iy * 128;
        for (int li = tid; li < 128 * 26; li += 256) {
            int r = li / 26, cc = li % 26;
            sd[r][cc] = dec[(size_t)(i0 + r) * 26 + cc];
        }
        __syncthreads();
        int n0 = nbase + tid, n1 = nbase + 256 + tid;
        bool a0 = n0 < VOCAB, a1 = n1 < VOCAB;
        float w0[26], w1[26], b0v = 0.f, b1v = 0.f;
        #pragma unroll
        for (int k = 0; k < 26; ++k) { w0[k] = 0.f; w1[k] = 0.f; }
        if (a0) { const float* w = outW + (size_t)n0 * 26;
            #pragma unroll
            for (int k = 0; k < 26; ++k) w0[k] = w[k];
            b0v = outb[n0]; }
        if (a1) { const float* w = outW + (size_t)n1 * 26;
            #pragma unroll
            for (int k = 0; k < 26; ++k) w1[k] = w[k];
            b1v = outb[n1]; }
        for (int i = 0; i < 128; ++i) {
            int grow = i0 + i;
            float acc0 = b0v, acc1 = b1v;
            const float* dr = sd[i];
            #pragma unroll
            for (int k = 0; k < 26; ++k) {
                float d = dr[k];
                acc0 = fmaf(d, w0[k], acc0);
                acc1 = fmaf(d, w1[k], acc1);
            }
            if (grow != 0) {                     // row 0 written later by k_row0
                size_t rb = (size_t)grow * VOCAB;
                if (a0) preds[rb + n0] = acc0;
                if (a1) preds[rb + n1] = acc1;
            }
        }
        return;
    }
    if (tid >= 64) return;
    // ---- recurrence (wave 0 of blocks 0,1) ----
    __builtin_amdgcn_s_setprio(3);
    int dir = bid, lane = tid;
    int row = lane & 15, gate = lane >> 4;
    bool rowok = row < HID;
    bool c0 = (lane & 16) != 0;
    bool c1 = (lane & 32) != 0;
    float kcv = (gate == 2) ? 2.f : 1.f;
    float msc = (gate == 2) ? 2.f * L2E : L2E;

    // --- runtime semantics detection (loop-invariant masks) ---
    // permlane16/32 swap: which output register holds the lane^16 / lane^32 value
    int ia = lane, ib = lane;
    asm("s_nop 1\n\tv_permlane16_swap_b32 %0, %1" : "+v"(ia), "+v"(ib));
    bool m16 = (ia == (lane ^ 16));
    int ja = lane, jb = lane;
    asm("s_nop 1\n\tv_permlane32_swap_b32 %0, %1" : "+v"(ja), "+v"(jb));
    bool m32 = (ja == (lane ^ 32));
    // DPP row_ror:1 direction: does lane i receive src[(i+1)&15] ?
    int rt = __builtin_amdgcn_update_dpp(row, row, 0x121, 0xF, 0xF, false);
    bool rplus = (__builtin_amdgcn_readfirstlane(rt) == 1);

    // --- per-lane permuted recurrent weights: wperm[j] = msc*W[g][ (row+/-j)&15 ] ---
    float wperm[16];
    #pragma unroll
    for (int j = 0; j < 16; ++j) {
        int colp = (row + j) & 15, colm = (row - j) & 15;
        int col = rplus ? colp : colm;
        float wv = 0.f;
        if (rowok && col < HID)
            wv = msc * Whh[(dir * G + gate * HID + row) * HID + col];
        wperm[j] = wv;
    }

    const float* ub = u + (size_t)dir * L * 64 + lane;
    int pstep = dir ? -64 : 64;
    int poff  = dir ? (L - 1) * 64 : 0;
    float h = 0.f, c = 0.f;
    float cur[8], nxt[8];
    #pragma unroll
    for (int k = 0; k < 8; ++k) cur[k] = ub[poff + k * pstep];
    #pragma unroll
    for (int k = 0; k < 8; ++k) nxt[k] = cur[k];

    for (int tcb = 0; tcb < L; tcb += 8) {
        if (tcb + 8 < L) {
            int p = poff + (tcb + 8) * pstep;
            #pragma unroll
            for (int k = 0; k < 8; ++k) nxt[k] = ub[p + k * pstep];
        }
        #pragma unroll
        for (int k = 0; k < 8; ++k) {
            // matvec: z = u_t + Whh_row . h  (h replicated per 16-row)
            float r1 = ROTF(h, 1),  r2 = ROTF(h, 2),  r3 = ROTF(h, 3);
            float r4 = ROTF(h, 4),  r5 = ROTF(h, 5),  r6 = ROTF(h, 6);
            float r7 = ROTF(h, 7),  r8 = ROTF(h, 8),  r9 = ROTF(h, 9);
            float r10 = ROTF(h, 10), r11 = ROTF(h, 11), r12 = ROTF(h, 12);
            float r13 = ROTF(h, 13), r14 = ROTF(h, 14), r15 = ROTF(h, 15);
            float a0 = fmaf(wperm[0], h, cur[k]);
            float a1 = wperm[1] * r1;
            float a2 = wperm[2] * r2;
            float a3 = wperm[3] * r3;
            a0 = fmaf(wperm[4],  r4,  a0); a1 = fmaf(wperm[5],  r5,  a1);
            a2 = fmaf(wperm[6],  r6,  a2); a3 = fmaf(wperm[7],  r7,  a3);
            a0 = fmaf(wperm[8],  r8,  a0); a1 = fmaf(wperm[9],  r9,  a1);
            a2 = fmaf(wperm[10], r10, a2); a3 = fmaf(wperm[11], r11, a3);
            a0 = fmaf(wperm[12], r12, a0); a1 = fmaf(wperm[13], r13, a1);
            a2 = fmaf(wperm[14], r14, a2); a3 = fmaf(wperm[15], r15, a3);
            float z = (a0 + a1) + (a2 + a3);        // pre-scaled by msc
            // own-gate activation
            float act = fmaf(-kcv, frcp(fexp2(z) + 1.f), 1.f);
            // gate exchange: every lane collects all 4 gate values of its row
            float pa = act, pb = act;
            asm("s_nop 1\n\tv_permlane16_swap_b32 %0, %1" : "+v"(pa), "+v"(pb));
            float p = m16 ? pa : pb;                // gate ^1
            float qa = act, qb = act;
            asm("s_nop 1\n\tv_permlane32_swap_b32 %0, %1" : "+v"(qa), "+v"(qb));
            float q = m32 ? qa : qb;                // gate ^2
            float ra = q, rb = q;
            asm("s_nop 1\n\tv_permlane16_swap_b32 %0, %1" : "+v"(ra), "+v"(rb));
            float rr = m16 ? ra : rb;               // gate ^3
            // role select: value of gate m is reg[(group)^m], regs={act,p,q,rr}
            float X  = c0 ? p : act;
            float Xp = c0 ? act : p;
            float Y  = c0 ? rr : q;
            float Yp = c0 ? q : rr;
            float si = c1 ? Y : X;
            float sf = c1 ? Yp : Xp;
            float tg = c1 ? X : Y;
            float so = c1 ? Xp : Yp;
            // cell update (all lanes, redundant across gate groups)
            float c2 = fmaf(sf, c, si * tg);
            float th = fmaf(-2.f, frcp(fexp2(c2 * (2.f * L2E)) + 1.f), 1.f);
            float hn = so * th;
            h = rowok ? hn : 0.f;
            c = c2;
            if (do_out0 && lane < HID) {
                int tg_ = dir ? (L - 1 - (tcb + k)) : (tcb + k);
                out0[(size_t)tg_ * (2 * HID) + dir * HID + lane] = h;
            }
        }
        #pragma unroll
        for (int k = 0; k < 8; ++k) cur[k] = nxt[k];
    }
    if (lane < HID) {
        finh[(chain_base + dir) * HID + lane] = h;
        finc[(chain_base + dir) * HID + lane] = c;
    }
}

// ---------------------------------------------------------------------------
// Kernel 4: u1 = msc*(Wih1 @ out0 + b1), padded [dir][L][64]
// ---------------------------------------------------------------------------
__global__ void k_u1(const float* __restrict__ out0, const float* __restrict__ Wih1,
                     const float* __restrict__ b1, float* __restrict__ u1)
{
    int idx = blockIdx.x * blockDim.x + threadIdx.x;
    if (idx >= L * 2 * 64) return;
    int t    = idx >> 7;
    int remv = idx & 127;
    int d1   = remv >> 6;
    int lane = remv & 63;
    int gate = lane >> 4, row = lane & 15;
    size_t oidx = ((size_t)d1 * L + t) * 64 + lane;
    if (row >= HID) { u1[oidx] = 0.f; return; }
    int g = gate * HID + row;
    float msc = (gate == 2) ? 2.f * L2E : L2E;
    float acc = b1[d1 * G + g];
    const float* w = Wih1 + (size_t)(d1 * G + g) * (2 * HID);
    const float* o = out0 + (size_t)t * (2 * HID);
    #pragma unroll
    for (int k = 0; k < 2 * HID; ++k)
        acc = fmaf(w[k], o[k], acc);
    u1[oidx] = msc * acc;
}

// ---------------------------------------------------------------------------
// Kernel 6: projections + decoder step 0 (with state) -> dec[0][0:26]
// ---------------------------------------------------------------------------
__global__ void __launch_bounds__(64) k_final(const float* __restrict__ fin_h, const float* __restrict__ fin_c,
                                              const float* __restrict__ p1W, const float* __restrict__ p1b,
                                              const float* __restrict__ p2W, const float* __restrict__ p2b,
                                              const float* __restrict__ dWih, const float* __restrict__ dWhh,
                                              const float* __restrict__ db, float* __restrict__ dec)
{
    __shared__ float sh[2 * HID], sc[2 * HID], sz[G];
    int tid = threadIdx.x;
    if (tid < 4 * HID) {
        int r = tid < 2 * HID ? tid : tid - 2 * HID;
        const float* W   = tid < 2 * HID ? p1W : p2W;
        const float* src = tid < 2 * HID ? fin_h : fin_c;
        float acc = tid < 2 * HID ? p1b[r] : p2b[r];
        for (int k = 0; k < 4 * HID; ++k) acc = fmaf(W[r * 4 * HID + k], src[k], acc);
        if (tid < 2 * HID) sh[r] = acc; else sc[r] = acc;
    }
    __syncthreads();
    for (int dir = 0; dir < 2; ++dir) {
        if (tid < G) {
            float acc = db[dir * G + tid] - dWih[dir * G + tid];   // input = -1.0
            for (int k = 0; k < HID; ++k)
                acc = fmaf(dWhh[(dir * G + tid) * HID + k], sh[dir * HID + k], acc);
            sz[tid] = acc;
        }
        __syncthreads();
        if (tid < HID) {
            float si = sigm(sz[tid]);
            float sf = sigm(sz[HID + tid]);
            float tg = tanh_(sz[2 * HID + tid]);
            float so = sigm(sz[3 * HID + tid]);
            float c2 = fmaf(sf, sc[dir * HID + tid], si * tg);
            dec[dir * HID + tid] = so * tanh_(c2);
        }
        __syncthreads();
    }
}

// ---------------------------------------------------------------------------
// Kernel 7: preds row 0 only
// ---------------------------------------------------------------------------
__global__ void k_row0(const float* __restrict__ dec, const float* __restrict__ outW,
                       const float* __restrict__ outb, float* __restrict__ preds)
{
    int n = blockIdx.x * blockDim.x + threadIdx.x;
    if (n >= VOCAB) return;
    float acc = outb[n];
    const float* w = outW + (size_t)n * 26;
    #pragma unroll
    for (int k = 0; k < 26; ++k) acc = fmaf(w[k], dec[k], acc);
    preds[n] = acc;
}

// ---------------------------------------------------------------------------
extern "C" void kernel_launch(void* const* d_in, const int* in_sizes, int n_in,
                              void* d_out, int out_size, void* d_ws, size_t ws_size,
                              hipStream_t stream)
{
    (void)in_sizes; (void)n_in; (void)out_size; (void)ws_size;

    const int*   x     = (const int*)d_in[0];
    const float* embW  = (const float*)d_in[1];
    const float* eWih0 = (const float*)d_in[2];
    const float* eWhh0 = (const float*)d_in[3];
    const float* eb0   = (const float*)d_in[4];
    const float* eWih1 = (const float*)d_in[5];
    const float* eWhh1 = (const float*)d_in[6];
    const float* eb1   = (const float*)d_in[7];
    const float* p1W   = (const float*)d_in[8];
    const float* p1b   = (const float*)d_in[9];
    const float* p2W   = (const float*)d_in[10];
    const float* p2b   = (const float*)d_in[11];
    const float* dWih  = (const float*)d_in[12];
    const float* dWhh  = (const float*)d_in[13];
    const float* db    = (const float*)d_in[14];
    const float* outW  = (const float*)d_in[15];
    const float* outb  = (const float*)d_in[16];

    float* ws    = (float*)d_ws;
    float* u0    = ws;                       // 2*L*64
    float* u1    = u0 + 2 * L * 64;          // 2*L*64
    float* out0  = u1 + 2 * L * 64;          // L*26
    float* dec   = out0 + L * 2 * HID;       // L*26
    float* fin_h = dec + L * 2 * HID;        // 52
    float* fin_c = fin_h + G;                // 52

    float* preds    = (float*)d_out;
    float* out_embs = preds + PRED_N;

    hipLaunchKernelGGL(k_emb_u0, dim3(L), dim3(128), 0, stream,
                       x, embW, eWih0, eb0, out_embs, u0);

    int restN = (L - 1) * 2 * HID;
    hipLaunchKernelGGL(k_rest, dim3((restN + 255) / 256), dim3(256), 0, stream, x, dWih, db, dec);

    hipLaunchKernelGGL(k_phase, dim3(2 + TILE_SPLIT), dim3(256), 0, stream,
                       u0, eWhh0, out0, fin_h, fin_c, 0, 1,
                       dec, outW, outb, preds, 0);

    hipLaunchKernelGGL(k_u1, dim3((L * 2 * 64 + 255) / 256), dim3(256), 0, stream,
                       out0, eWih1, eb1, u1);

    hipLaunchKernelGGL(k_phase, dim3(2 + (NTILE - TILE_SPLIT)), dim3(256), 0, stream,
                       u1, eWhh1, (float*)nullptr, fin_h, fin_c, 2, 0,
                       dec, outW, outb, preds, TILE_SPLIT);

    hipLaunchKernelGGL(k_final, dim3(1), dim3(64), 0, stream,
                       fin_h, fin_c, p1W, p1b, p2W, p2b, dWih, dWhh, db, dec);

    hipLaunchKernelGGL(k_row0, dim3((VOCAB + 255) / 256), dim3(256), 0, stream,
                       dec, outW, outb, preds);
}

// Round 6
// 713.877 us; speedup vs baseline: 1.2691x; 1.2691x over previous
//
#include <hip/hip_runtime.h>
#include <hip/hip_bf16.h>
#include <cstdint>
#include <cstddef>

#define L      2048
#define IN_DIM 256
#define HID    13
#define G      52            // 4*HID
#define VOCAB  50257
#define PRED_N ((size_t)L * VOCAB)
#define L2E    1.4426950408889634f
#define INV2L2E 0.34657359027997264f
#define NTX    99            // x-tiles of 512 cols (99*512 >= 50257)
#define NTY    16            // y-tiles of 128 rows
#define NTILE  (NTX * NTY)   // 1584
#define TILE_SPLIT (NTILE / 2)
#define SPIN_CAP 20000

static __device__ __forceinline__ float fexp2(float x) { return __builtin_amdgcn_exp2f(x); }
static __device__ __forceinline__ float frcp(float x) { return __builtin_amdgcn_rcpf(x); }
static __device__ __forceinline__ float sigm(float z) { return 1.f - frcp(fexp2(z * L2E) + 1.f); }
static __device__ __forceinline__ float tanh_(float z) { return 1.f - 2.f * frcp(fexp2(z * (2.f * L2E)) + 1.f); }
static __device__ __forceinline__ float bcast(float v, int l) {
    return __int_as_float(__builtin_amdgcn_readlane(__float_as_int(v), l));
}

// ---------------------------------------------------------------------------
// Kernel 1: embedding gather (-> d_out embs section, f32) + u0 = msc*(Wih0@emb+b0)
// padded layout [dir][L][64]; grid = L blocks, 128 threads. Also zeroes flags.
// ---------------------------------------------------------------------------
__global__ void k_emb_u0(const int* __restrict__ x, const float* __restrict__ embW,
                         const float* __restrict__ Wih0, const float* __restrict__ b0,
                         float* __restrict__ out_embs, float* __restrict__ u0,
                         int* __restrict__ flags)
{
    __shared__ float se[IN_DIM];
    int t = blockIdx.x;
    int tid = threadIdx.x;            // 128
    if (t == 0 && tid == 0) { flags[0] = 0; flags[1] = 0; }
    int rowx = x[t];
    float2 e = ((const float2*)(embW + (size_t)rowx * IN_DIM))[tid];
    se[2 * tid]     = e.x;
    se[2 * tid + 1] = e.y;
    ((float2*)(out_embs + (size_t)t * IN_DIM))[tid] = e;
    __syncthreads();
    if (tid < 2 * G) {
        int dirg = tid / G, g = tid % G;
        int gate = g / HID, row = g % HID;
        float msc = (gate == 2) ? 2.f * L2E : L2E;
        float acc = b0[dirg * G + g];
        const float* w = Wih0 + (size_t)(dirg * G + g) * IN_DIM;
        #pragma unroll 8
        for (int k = 0; k < IN_DIM; ++k)
            acc = fmaf(w[k], se[k], acc);
        u0[((size_t)dirg * L + t) * 64 + gate * 16 + row] = msc * acc;
    } else {
        int p = tid - 2 * G;          // 0..23 -> zero the 2*12 pad slots
        int dirp = p / 12, pp = p % 12;
        int gate = pp / 3, row = HID + pp % 3;
        u0[((size_t)dirp * L + t) * 64 + gate * 16 + row] = 0.f;
    }
}

// ---------------------------------------------------------------------------
// Kernel 2: decoder rows 1..L-1 (zero-state cells, parallel). dec[i][j], j<26
// ---------------------------------------------------------------------------
__global__ void k_rest(const int* __restrict__ x, const float* __restrict__ dWih,
                       const float* __restrict__ db, float* __restrict__ dec)
{
    int idx = blockIdx.x * blockDim.x + threadIdx.x;
    if (idx >= (L - 1) * 2 * HID) return;
    int i = idx / (2 * HID) + 1;
    int j = idx % (2 * HID);
    int dir = j / HID, jj = j % HID;
    float v = (float)x[i - 1];
    int base = dir * G;
    float zi = fmaf(dWih[base + jj],           v, db[base + jj]);
    float zg = fmaf(dWih[base + 2 * HID + jj], v, db[base + 2 * HID + jj]);
    float zo = fmaf(dWih[base + 3 * HID + jj], v, db[base + 3 * HID + jj]);
    float c2 = sigm(zi) * tanh_(zg);
    dec[(size_t)i * (2 * HID) + j] = sigm(zo) * tanh_(c2);
}

// ---------------------------------------------------------------------------
// Kernel 3/5: blocks 0,1 = one LSTM direction each (1 wave, round-4 structure:
// permlane gate exchange + readlane h broadcast; c tracked in 2*L2E units).
// blocks >=2 = output-GEMM tiles; after finishing, they SPIN-HEAT (dependent
// FMA loop) until both chains signal done -> holds DVFS clocks at boost.
// ---------------------------------------------------------------------------
__global__ void __launch_bounds__(256) k_phase(
    const float* __restrict__ u, const float* __restrict__ Whh,
    float* __restrict__ out0, float* __restrict__ finh, float* __restrict__ finc,
    int chain_base, int do_out0,
    const float* __restrict__ dec, const float* __restrict__ outW,
    const float* __restrict__ outb, float* __restrict__ preds, int tile_base,
    int* __restrict__ flag, float* __restrict__ wsdump)
{
    __shared__ float sd[128][28];
    int bid = blockIdx.x;
    int tid = threadIdx.x;
    if (bid >= 2) {
        // ---- output-GEMM tile ----
        __builtin_amdgcn_s_setprio(0);
        int tile = bid - 2 + tile_base;
        int ix = tile % NTX, iy = tile / NTX;
        int nbase = ix * 512, i0 = iy * 128;
        for (int li = tid; li < 128 * 26; li += 256) {
            int r = li / 26, cc = li % 26;
            sd[r][cc] = dec[(size_t)(i0 + r) * 26 + cc];
        }
        __syncthreads();
        int n0 = nbase + tid, n1 = nbase + 256 + tid;
        bool a0 = n0 < VOCAB, a1 = n1 < VOCAB;
        float w0[26], w1[26], b0v = 0.f, b1v = 0.f;
        #pragma unroll
        for (int k = 0; k < 26; ++k) { w0[k] = 0.f; w1[k] = 0.f; }
        if (a0) { const float* w = outW + (size_t)n0 * 26;
            #pragma unroll
            for (int k = 0; k < 26; ++k) w0[k] = w[k];
            b0v = outb[n0]; }
        if (a1) { const float* w = outW + (size_t)n1 * 26;
            #pragma unroll
            for (int k = 0; k < 26; ++k) w1[k] = w[k];
            b1v = outb[n1]; }
        for (int i = 0; i < 128; ++i) {
            int grow = i0 + i;
            float acc0 = b0v, acc1 = b1v;
            const float* dr = sd[i];
            #pragma unroll
            for (int k = 0; k < 26; ++k) {
                float d = dr[k];
                acc0 = fmaf(d, w0[k], acc0);
                acc1 = fmaf(d, w1[k], acc1);
            }
            if (grow != 0) {                     // row 0 written later by k_row0
                size_t rb = (size_t)grow * VOCAB;
                if (a0) preds[rb + n0] = acc0;
                if (a1) preds[rb + n1] = acc1;
            }
        }
        // ---- heater spin: keep clocks up until recurrence chains finish ----
        float dummy = (float)(tid + 1);
        for (int it = 0; it < SPIN_CAP; ++it) {
            int fv = 0;
            if ((tid & 63) == 0)
                fv = __hip_atomic_load(flag, __ATOMIC_RELAXED, __HIP_MEMORY_SCOPE_AGENT);
            fv = __builtin_amdgcn_readfirstlane(fv);
            if (fv >= 2) break;
            #pragma unroll
            for (int j = 0; j < 64; ++j)
                dummy = fmaf(dummy, 1.0000001f, 0.0000001f);
        }
        wsdump[bid] = dummy;    // never read; keeps the loop alive
        return;
    }
    if (tid >= 64) return;
    // ---- recurrence (wave 0 of blocks 0,1) ----
    __builtin_amdgcn_s_setprio(3);
    int dir = bid, lane = tid;
    int lg16 = lane & 15, gate = lane >> 4;
    int rsrc = gate * HID + (lg16 < HID ? lg16 : HID - 1);   // clamp
    // act constants: i-gate pre-scaled by 2*L2E (so prod = 2L2E*si*tg);
    // g-gate tanh (k=2); f,o plain sigmoid
    float kcv, onev;
    if (gate == 2)      { kcv = 2.f;        onev = 1.f; }
    else if (gate == 0) { kcv = 2.f * L2E;  onev = 2.f * L2E; }
    else                { kcv = 1.f;        onev = 1.f; }
    float whh[HID];
    #pragma unroll
    for (int k = 0; k < HID; ++k) whh[k] = ((gate == 2) ? 2.f * L2E : L2E) * Whh[(dir * G + rsrc) * HID + k];

    // runtime detection of permlane swap operand direction (wave-uniform)
    int ia = lane, ib = lane;
    asm("s_nop 1\n\tv_permlane16_swap_b32 %0, %1" : "+v"(ia), "+v"(ib));
    bool m16 = (ia == (lane ^ 16));
    int ja = lane, jb = lane;
    asm("s_nop 1\n\tv_permlane32_swap_b32 %0, %1" : "+v"(ja), "+v"(jb));
    bool m32 = (ja == (lane ^ 32));

    const float* ub = u + (size_t)dir * L * 64 + lane;
    int pstep = dir ? -64 : 64;
    int poff  = dir ? (L - 1) * 64 : 0;
    float h = 0.f, c = 0.f;      // c in 2*L2E units
    float cur[8], nxt[8];
    #pragma unroll
    for (int k = 0; k < 8; ++k) cur[k] = ub[poff + k * pstep];
    #pragma unroll
    for (int k = 0; k < 8; ++k) nxt[k] = cur[k];

    for (int tcb = 0; tcb < L; tcb += 8) {
        if (tcb + 8 < L) {
            int p = poff + (tcb + 8) * pstep;
            #pragma unroll
            for (int k = 0; k < 8; ++k) nxt[k] = ub[p + k * pstep];
        }
        #pragma unroll
        for (int k = 0; k < 8; ++k) {
            float h0 = bcast(h, 0), h1 = bcast(h, 1), h2 = bcast(h, 2), h3 = bcast(h, 3);
            float h4 = bcast(h, 4), h5 = bcast(h, 5), h6 = bcast(h, 6), h7 = bcast(h, 7);
            float h8 = bcast(h, 8), h9 = bcast(h, 9), h10 = bcast(h, 10), h11 = bcast(h, 11);
            float h12 = bcast(h, 12);
            float A = fmaf(whh[0], h0, cur[k]);
            float B = whh[1] * h1;
            float C = whh[2] * h2;
            float D = whh[3] * h3;
            A = fmaf(whh[4], h4, A);   B = fmaf(whh[5], h5, B);
            C = fmaf(whh[6], h6, C);   D = fmaf(whh[7], h7, D);
            A = fmaf(whh[8], h8, A);   B = fmaf(whh[9], h9, B);
            C = fmaf(whh[10], h10, C); D = fmaf(whh[11], h11, D);
            A = fmaf(whh[12], h12, A);
            float z = (A + B) + (C + D);              // pre-scaled by msc
            float act = fmaf(-kcv, frcp(fexp2(z) + 1.f), onev);
            float pa = act, pb = act;
            asm("s_nop 1\n\tv_permlane16_swap_b32 %0, %1" : "+v"(pa), "+v"(pb));
            float sf = m16 ? pa : pb;                 // act[lane^16] (f for grp0)
            float qa = act, qb = act;
            asm("s_nop 1\n\tv_permlane32_swap_b32 %0, %1" : "+v"(qa), "+v"(qb));
            float tg = m32 ? qa : qb;                 // act[lane^32] (g for grp0)
            float ra = tg, rb = tg;
            asm("s_nop 1\n\tv_permlane16_swap_b32 %0, %1" : "+v"(ra), "+v"(rb));
            float so = m16 ? ra : rb;                 // act[lane^48] (o for grp0)
            float c2 = fmaf(sf, c, act * tg);         // 2*L2E units (grp0 lanes valid)
            float th = fmaf(-2.f, frcp(fexp2(c2) + 1.f), 1.f);
            h = so * th;
            c = c2;
            if (do_out0 && lane < HID) {
                int tg_ = dir ? (L - 1 - (tcb + k)) : (tcb + k);
                out0[(size_t)tg_ * (2 * HID) + dir * HID + lane] = h;
            }
        }
        #pragma unroll
        for (int k = 0; k < 8; ++k) cur[k] = nxt[k];
    }
    if (lane < HID) {
        finh[(chain_base + dir) * HID + lane] = h;
        finc[(chain_base + dir) * HID + lane] = c * INV2L2E;
    }
    __threadfence();
    if (lane == 0)
        __hip_atomic_fetch_add(flag, 1, __ATOMIC_RELEASE, __HIP_MEMORY_SCOPE_AGENT);
}

// ---------------------------------------------------------------------------
// Kernel 4: u1 = msc*(Wih1 @ out0 + b1), padded [dir][L][64]
// ---------------------------------------------------------------------------
__global__ void k_u1(const float* __restrict__ out0, const float* __restrict__ Wih1,
                     const float* __restrict__ b1, float* __restrict__ u1)
{
    int idx = blockIdx.x * blockDim.x + threadIdx.x;
    if (idx >= L * 2 * 64) return;
    int t    = idx >> 7;
    int remv = idx & 127;
    int d1   = remv >> 6;
    int lane = remv & 63;
    int gate = lane >> 4, row = lane & 15;
    size_t oidx = ((size_t)d1 * L + t) * 64 + lane;
    if (row >= HID) { u1[oidx] = 0.f; return; }
    int g = gate * HID + row;
    float msc = (gate == 2) ? 2.f * L2E : L2E;
    float acc = b1[d1 * G + g];
    const float* w = Wih1 + (size_t)(d1 * G + g) * (2 * HID);
    const float* o = out0 + (size_t)t * (2 * HID);
    #pragma unroll
    for (int k = 0; k < 2 * HID; ++k)
        acc = fmaf(w[k], o[k], acc);
    u1[oidx] = msc * acc;
}

// ---------------------------------------------------------------------------
// Kernel 6: projections + decoder step 0 (with state) -> dec[0][0:26]
// ---------------------------------------------------------------------------
__global__ void __launch_bounds__(64) k_final(const float* __restrict__ fin_h, const float* __restrict__ fin_c,
                                              const float* __restrict__ p1W, const float* __restrict__ p1b,
                                              const float* __restrict__ p2W, const float* __restrict__ p2b,
                                              const float* __restrict__ dWih, const float* __restrict__ dWhh,
                                              const float* __restrict__ db, float* __restrict__ dec)
{
    __shared__ float sh[2 * HID], sc[2 * HID], sz[G];
    int tid = threadIdx.x;
    if (tid < 4 * HID) {
        int r = tid < 2 * HID ? tid : tid - 2 * HID;
        const float* W   = tid < 2 * HID ? p1W : p2W;
        const float* src = tid < 2 * HID ? fin_h : fin_c;
        float acc = tid < 2 * HID ? p1b[r] : p2b[r];
        for (int k = 0; k < 4 * HID; ++k) acc = fmaf(W[r * 4 * HID + k], src[k], acc);
        if (tid < 2 * HID) sh[r] = acc; else sc[r] = acc;
    }
    __syncthreads();
    for (int dir = 0; dir < 2; ++dir) {
        if (tid < G) {
            float acc = db[dir * G + tid] - dWih[dir * G + tid];   // input = -1.0
            for (int k = 0; k < HID; ++k)
                acc = fmaf(dWhh[(dir * G + tid) * HID + k], sh[dir * HID + k], acc);
            sz[tid] = acc;
        }
        __syncthreads();
        if (tid < HID) {
            float si = sigm(sz[tid]);
            float sf = sigm(sz[HID + tid]);
            float tg = tanh_(sz[2 * HID + tid]);
            float so = sigm(sz[3 * HID + tid]);
            float c2 = fmaf(sf, sc[dir * HID + tid], si * tg);
            dec[dir * HID + tid] = so * tanh_(c2);
        }
        __syncthreads();
    }
}

// ---------------------------------------------------------------------------
// Kernel 7: preds row 0 only
// ---------------------------------------------------------------------------
__global__ void k_row0(const float* __restrict__ dec, const float* __restrict__ outW,
                       const float* __restrict__ outb, float* __restrict__ preds)
{
    int n = blockIdx.x * blockDim.x + threadIdx.x;
    if (n >= VOCAB) return;
    float acc = outb[n];
    const float* w = outW + (size_t)n * 26;
    #pragma unroll
    for (int k = 0; k < 26; ++k) acc = fmaf(w[k], dec[k], acc);
    preds[n] = acc;
}

// ---------------------------------------------------------------------------
extern "C" void kernel_launch(void* const* d_in, const int* in_sizes, int n_in,
                              void* d_out, int out_size, void* d_ws, size_t ws_size,
                              hipStream_t stream)
{
    (void)in_sizes; (void)n_in; (void)out_size; (void)ws_size;

    const int*   x     = (const int*)d_in[0];
    const float* embW  = (const float*)d_in[1];
    const float* eWih0 = (const float*)d_in[2];
    const float* eWhh0 = (const float*)d_in[3];
    const float* eb0   = (const float*)d_in[4];
    const float* eWih1 = (const float*)d_in[5];
    const float* eWhh1 = (const float*)d_in[6];
    const float* eb1   = (const float*)d_in[7];
    const float* p1W   = (const float*)d_in[8];
    const float* p1b   = (const float*)d_in[9];
    const float* p2W   = (const float*)d_in[10];
    const float* p2b   = (const float*)d_in[11];
    const float* dWih  = (const float*)d_in[12];
    const float* dWhh  = (const float*)d_in[13];
    const float* db    = (const float*)d_in[14];
    const float* outW  = (const float*)d_in[15];
    const float* outb  = (const float*)d_in[16];

    float* ws    = (float*)d_ws;
    float* u0    = ws;                       // 2*L*64
    float* u1    = u0 + 2 * L * 64;          // 2*L*64
    float* out0  = u1 + 2 * L * 64;          // L*26
    float* dec   = out0 + L * 2 * HID;       // L*26
    float* fin_h = dec + L * 2 * HID;        // 52
    float* fin_c = fin_h + G;                // 52
    int*   flags = (int*)(fin_c + G);        // 2
    float* wsdump = (float*)(flags + 2);     // ~NTILE+8

    float* preds    = (float*)d_out;
    float* out_embs = preds + PRED_N;

    hipLaunchKernelGGL(k_emb_u0, dim3(L), dim3(128), 0, stream,
                       x, embW, eWih0, eb0, out_embs, u0, flags);

    int restN = (L - 1) * 2 * HID;
    hipLaunchKernelGGL(k_rest, dim3((restN + 255) / 256), dim3(256), 0, stream, x, dWih, db, dec);

    hipLaunchKernelGGL(k_phase, dim3(2 + TILE_SPLIT), dim3(256), 0, stream,
                       u0, eWhh0, out0, fin_h, fin_c, 0, 1,
                       dec, outW, outb, preds, 0, flags + 0, wsdump);

    hipLaunchKernelGGL(k_u1, dim3((L * 2 * 64 + 255) / 256), dim3(256), 0, stream,
                       out0, eWih1, eb1, u1);

    hipLaunchKernelGGL(k_phase, dim3(2 + (NTILE - TILE_SPLIT)), dim3(256), 0, stream,
                       u1, eWhh1, (float*)nullptr, fin_h, fin_c, 2, 0,
                       dec, outW, outb, preds, TILE_SPLIT, flags + 1, wsdump);

    hipLaunchKernelGGL(k_final, dim3(1), dim3(64), 0, stream,
                       fin_h, fin_c, p1W, p1b, p2W, p2b, dWih, dWhh, db, dec);

    hipLaunchKernelGGL(k_row0, dim3((VOCAB + 255) / 256), dim3(256), 0, stream,
                       dec, outW, outb, preds);
}

// Round 8
// 611.316 us; speedup vs baseline: 1.4820x; 1.1678x over previous
//
#include <hip/hip_runtime.h>
#include <hip/hip_bf16.h>
#include <cstdint>
#include <cstddef>

#define L      2048
#define IN_DIM 256
#define HID    13
#define G      52            // 4*HID
#define VOCAB  50257
#define PRED_N ((size_t)L * VOCAB)
#define L2E    1.4426950408889634f
#define INV2L2E 0.34657359027997264f
#define NTX    99            // x-tiles of 512 cols (99*512 >= 50257)
#define NTY    16            // y-tiles of 128 rows
#define NTILE  (NTX * NTY)   // 1584

static __device__ __forceinline__ float fexp2(float x) { return __builtin_amdgcn_exp2f(x); }
static __device__ __forceinline__ float frcp(float x) { return __builtin_amdgcn_rcpf(x); }
static __device__ __forceinline__ float sigm(float z) { return 1.f - frcp(fexp2(z * L2E) + 1.f); }
static __device__ __forceinline__ float tanh_(float z) { return 1.f - 2.f * frcp(fexp2(z * (2.f * L2E)) + 1.f); }
static __device__ __forceinline__ float bcast(float v, int l) {
    return __int_as_float(__builtin_amdgcn_readlane(__float_as_int(v), l));
}

// ---------------------------------------------------------------------------
// Kernel 1: embedding gather (-> d_out embs section, f32) + u0 = msc*(Wih0@emb+b0)
// padded layout [dir][L][64]; grid = L blocks, 128 threads
// ---------------------------------------------------------------------------
__global__ void k_emb_u0(const int* __restrict__ x, const float* __restrict__ embW,
                         const float* __restrict__ Wih0, const float* __restrict__ b0,
                         float* __restrict__ out_embs, float* __restrict__ u0)
{
    __shared__ float se[IN_DIM];
    int t = blockIdx.x;
    int tid = threadIdx.x;            // 128
    int rowx = x[t];
    float2 e = ((const float2*)(embW + (size_t)rowx * IN_DIM))[tid];
    se[2 * tid]     = e.x;
    se[2 * tid + 1] = e.y;
    ((float2*)(out_embs + (size_t)t * IN_DIM))[tid] = e;
    __syncthreads();
    if (tid < 2 * G) {
        int dirg = tid / G, g = tid % G;
        int gate = g / HID, row = g % HID;
        float msc = (gate == 2) ? 2.f * L2E : L2E;
        float acc = b0[dirg * G + g];
        const float* w = Wih0 + (size_t)(dirg * G + g) * IN_DIM;
        #pragma unroll 8
        for (int k = 0; k < IN_DIM; ++k)
            acc = fmaf(w[k], se[k], acc);
        u0[((size_t)dirg * L + t) * 64 + gate * 16 + row] = msc * acc;
    } else {
        int p = tid - 2 * G;          // 0..23 -> zero the 2*12 pad slots
        int dirp = p / 12, pp = p % 12;
        int gate = pp / 3, row = HID + pp % 3;
        u0[((size_t)dirp * L + t) * 64 + gate * 16 + row] = 0.f;
    }
}

// ---------------------------------------------------------------------------
// Kernel 2: decoder rows 1..L-1 (zero-state cells, parallel). dec[i][j], j<26
// ---------------------------------------------------------------------------
__global__ void k_rest(const int* __restrict__ x, const float* __restrict__ dWih,
                       const float* __restrict__ db, float* __restrict__ dec)
{
    int idx = blockIdx.x * blockDim.x + threadIdx.x;
    if (idx >= (L - 1) * 2 * HID) return;
    int i = idx / (2 * HID) + 1;
    int j = idx % (2 * HID);
    int dir = j / HID, jj = j % HID;
    float v = (float)x[i - 1];
    int base = dir * G;
    float zi = fmaf(dWih[base + jj],           v, db[base + jj]);
    float zg = fmaf(dWih[base + 2 * HID + jj], v, db[base + 2 * HID + jj]);
    float zo = fmaf(dWih[base + 3 * HID + jj], v, db[base + 3 * HID + jj]);
    float c2 = sigm(zi) * tanh_(zg);
    dec[(size_t)i * (2 * HID) + j] = sigm(zo) * tanh_(c2);
}

// ---------------------------------------------------------------------------
// Recurrence body: per-lane cndmask selects (m16/m32 are LANE-VARYING — the
// round-7 uniform-branch transform was invalid). Template only on DOUT
// (wave-uniform). c tracked in 2*L2E units (i-gate prescaled).
// ---------------------------------------------------------------------------
template<bool DOUT>
static __device__ __forceinline__ void chain_run(
    const float* __restrict__ ub, int pstep,
    const float* __restrict__ whh, float kcv, float onev,
    bool m16, bool m32,
    float* __restrict__ outp,
    float& hout, float& cout)
{
    float h = 0.f, c = 0.f;      // c in 2*L2E units
    float cur[8], nxt[8];
    #pragma unroll
    for (int k = 0; k < 8; ++k) cur[k] = ub[k * pstep];
    #pragma unroll
    for (int k = 0; k < 8; ++k) nxt[k] = cur[k];
    const float* upf = ub + (ptrdiff_t)8 * pstep;

    for (int tcb = 0; tcb < L; tcb += 8) {
        if (tcb + 8 < L) {
            #pragma unroll
            for (int k = 0; k < 8; ++k) nxt[k] = upf[k * pstep];
            upf += (ptrdiff_t)8 * pstep;
        }
        #pragma unroll
        for (int k = 0; k < 8; ++k) {
            float h0 = bcast(h, 0), h1 = bcast(h, 1), h2 = bcast(h, 2), h3 = bcast(h, 3);
            float h4 = bcast(h, 4), h5 = bcast(h, 5), h6 = bcast(h, 6), h7 = bcast(h, 7);
            float h8 = bcast(h, 8), h9 = bcast(h, 9), h10 = bcast(h, 10), h11 = bcast(h, 11);
            float h12 = bcast(h, 12);
            float A = fmaf(whh[0], h0, cur[k]);
            float B = whh[1] * h1;
            float C = whh[2] * h2;
            float D = whh[3] * h3;
            A = fmaf(whh[4], h4, A);   B = fmaf(whh[5], h5, B);
            C = fmaf(whh[6], h6, C);   D = fmaf(whh[7], h7, D);
            A = fmaf(whh[8], h8, A);   B = fmaf(whh[9], h9, B);
            C = fmaf(whh[10], h10, C); D = fmaf(whh[11], h11, D);
            A = fmaf(whh[12], h12, A);
            float z = (A + B) + (C + D);              // pre-scaled
            float act = fmaf(-kcv, frcp(fexp2(z) + 1.f), onev);
            float pa = act, pb = act;
            asm("s_nop 1\n\tv_permlane16_swap_b32 %0, %1" : "+v"(pa), "+v"(pb));
            float sf = m16 ? pa : pb;                 // act[lane^16]
            float qa = act, qb = act;
            asm("s_nop 1\n\tv_permlane32_swap_b32 %0, %1" : "+v"(qa), "+v"(qb));
            float tg = m32 ? qa : qb;                 // act[lane^32]
            float ra = tg, rb = tg;
            asm("s_nop 1\n\tv_permlane16_swap_b32 %0, %1" : "+v"(ra), "+v"(rb));
            float so = m16 ? ra : rb;                 // act[lane^48]
            float c2 = fmaf(sf, c, act * tg);         // 2*L2E units (grp0 valid)
            float th = fmaf(-2.f, frcp(fexp2(c2) + 1.f), 1.f);
            h = so * th;
            c = c2;
            if (DOUT) { *outp = h; outp += pstep; }
        }
        #pragma unroll
        for (int k = 0; k < 8; ++k) cur[k] = nxt[k];
    }
    hout = h; cout = c;
}

static __device__ __forceinline__ void chain_setup_and_run(
    const float* __restrict__ u, const float* __restrict__ Whh,
    float* __restrict__ out0p, float* __restrict__ finh, float* __restrict__ finc,
    int chain_base, int do_out0, int dir, int lane)
{
    int lg16 = lane & 15, gate = lane >> 4;
    int rsrc = gate * HID + (lg16 < HID ? lg16 : HID - 1);   // clamp
    float kcv, onev;
    if (gate == 2)      { kcv = 2.f;        onev = 1.f; }         // g: tanh
    else if (gate == 0) { kcv = 2.f * L2E;  onev = 2.f * L2E; }   // i: prescaled sigmoid
    else                { kcv = 1.f;        onev = 1.f; }         // f,o: sigmoid
    float msc = (gate == 2) ? 2.f * L2E : L2E;
    float whh[HID];
    #pragma unroll
    for (int k = 0; k < HID; ++k) whh[k] = msc * Whh[(dir * G + rsrc) * HID + k];

    // runtime detection of permlane swap result placement (PER-LANE masks)
    int ia = lane, ib = lane;
    asm("s_nop 1\n\tv_permlane16_swap_b32 %0, %1" : "+v"(ia), "+v"(ib));
    bool m16 = (ia == (lane ^ 16));
    int ja = lane, jb = lane;
    asm("s_nop 1\n\tv_permlane32_swap_b32 %0, %1" : "+v"(ja), "+v"(jb));
    bool m32 = (ja == (lane ^ 32));

    const float* ub = u + (size_t)dir * L * 64 + (dir ? (size_t)(L - 1) * 64 : 0) + lane;
    int pstep = dir ? -64 : 64;
    float* outp = out0p + ((size_t)dir * L + (dir ? L - 1 : 0)) * 64 + lane;

    float h, c;
    if (do_out0) chain_run<true >(ub, pstep, whh, kcv, onev, m16, m32, outp, h, c);
    else         chain_run<false>(ub, pstep, whh, kcv, onev, m16, m32, outp, h, c);

    if (lane < HID) {
        finh[(chain_base + dir) * HID + lane] = h;
        finc[(chain_base + dir) * HID + lane] = c * INV2L2E;
    }
}

// ---------------------------------------------------------------------------
// Kernel 3 (phase 0): blocks 0,1 = layer-0 chains; blocks >=2 = ALL 1584
// output-GEMM tiles (rows 1..L-1) cohabiting with the chains.
// ---------------------------------------------------------------------------
__global__ void __launch_bounds__(256) k_phase0(
    const float* __restrict__ u, const float* __restrict__ Whh,
    float* __restrict__ out0p, float* __restrict__ finh, float* __restrict__ finc,
    const float* __restrict__ dec, const float* __restrict__ outW,
    const float* __restrict__ outb, float* __restrict__ preds)
{
    __shared__ float sd[128][28];
    int bid = blockIdx.x;
    int tid = threadIdx.x;
    if (bid >= 2) {
        // ---- output-GEMM tile ----
        __builtin_amdgcn_s_setprio(0);
        int tile = bid - 2;
        int ix = tile % NTX, iy = tile / NTX;
        int nbase = ix * 512, i0 = iy * 128;
        for (int li = tid; li < 128 * 26; li += 256) {
            int r = li / 26, cc = li % 26;
            sd[r][cc] = dec[(size_t)(i0 + r) * 26 + cc];
        }
        __syncthreads();
        int n0 = nbase + tid, n1 = nbase + 256 + tid;
        bool a0 = n0 < VOCAB, a1 = n1 < VOCAB;
        float w0[26], w1[26], b0v = 0.f, b1v = 0.f;
        #pragma unroll
        for (int k = 0; k < 26; ++k) { w0[k] = 0.f; w1[k] = 0.f; }
        if (a0) { const float* w = outW + (size_t)n0 * 26;
            #pragma unroll
            for (int k = 0; k < 26; ++k) w0[k] = w[k];
            b0v = outb[n0]; }
        if (a1) { const float* w = outW + (size_t)n1 * 26;
            #pragma unroll
            for (int k = 0; k < 26; ++k) w1[k] = w[k];
            b1v = outb[n1]; }
        for (int i = 0; i < 128; ++i) {
            int grow = i0 + i;
            float acc0 = b0v, acc1 = b1v;
            const float* dr = sd[i];
            #pragma unroll
            for (int k = 0; k < 26; ++k) {
                float d = dr[k];
                acc0 = fmaf(d, w0[k], acc0);
                acc1 = fmaf(d, w1[k], acc1);
            }
            if (grow != 0) {                     // row 0 written later by k_row0
                size_t rb = (size_t)grow * VOCAB;
                if (a0) preds[rb + n0] = acc0;
                if (a1) preds[rb + n1] = acc1;
            }
        }
        return;
    }
    if (tid >= 64) return;
    __builtin_amdgcn_s_setprio(3);
    chain_setup_and_run(u, Whh, out0p, finh, finc, 0, 1, bid, tid);
}

// ---------------------------------------------------------------------------
// Kernel 5 (phase 1): chain-only, 2 blocks x 64 (clean chain-time readout)
// ---------------------------------------------------------------------------
__global__ void __launch_bounds__(64) k_phase1(
    const float* __restrict__ u, const float* __restrict__ Whh,
    float* __restrict__ finh, float* __restrict__ finc)
{
    chain_setup_and_run(u, Whh, (float*)nullptr, finh, finc, 2, 0, blockIdx.x, threadIdx.x);
}

// ---------------------------------------------------------------------------
// Kernel 4: u1 = msc*(Wih1 @ out0 + b1), out0p padded [dir][L][64]
// ---------------------------------------------------------------------------
__global__ void k_u1(const float* __restrict__ out0p, const float* __restrict__ Wih1,
                     const float* __restrict__ b1, float* __restrict__ u1)
{
    int idx = blockIdx.x * blockDim.x + threadIdx.x;
    if (idx >= L * 2 * 64) return;
    int t    = idx >> 7;
    int remv = idx & 127;
    int d1   = remv >> 6;
    int lane = remv & 63;
    int gate = lane >> 4, row = lane & 15;
    size_t oidx = ((size_t)d1 * L + t) * 64 + lane;
    if (row >= HID) { u1[oidx] = 0.f; return; }
    int g = gate * HID + row;
    float msc = (gate == 2) ? 2.f * L2E : L2E;
    float acc = b1[d1 * G + g];
    const float* w = Wih1 + (size_t)(d1 * G + g) * (2 * HID);
    const float* o0 = out0p + (size_t)t * 64;            // dir0 h at lanes 0..12
    const float* o1 = out0p + ((size_t)L + t) * 64;      // dir1 h at lanes 0..12
    #pragma unroll
    for (int k = 0; k < HID; ++k)
        acc = fmaf(w[k], o0[k], acc);
    #pragma unroll
    for (int k = 0; k < HID; ++k)
        acc = fmaf(w[HID + k], o1[k], acc);
    u1[oidx] = msc * acc;
}

// ---------------------------------------------------------------------------
// Kernel 6: projections + decoder step 0 (with state) -> dec[0][0:26]
// ---------------------------------------------------------------------------
__global__ void __launch_bounds__(64) k_final(const float* __restrict__ fin_h, const float* __restrict__ fin_c,
                                              const float* __restrict__ p1W, const float* __restrict__ p1b,
                                              const float* __restrict__ p2W, const float* __restrict__ p2b,
                                              const float* __restrict__ dWih, const float* __restrict__ dWhh,
                                              const float* __restrict__ db, float* __restrict__ dec)
{
    __shared__ float sh[2 * HID], sc[2 * HID], sz[G];
    int tid = threadIdx.x;
    if (tid < 4 * HID) {
        int r = tid < 2 * HID ? tid : tid - 2 * HID;
        const float* W   = tid < 2 * HID ? p1W : p2W;
        const float* src = tid < 2 * HID ? fin_h : fin_c;
        float acc = tid < 2 * HID ? p1b[r] : p2b[r];
        for (int k = 0; k < 4 * HID; ++k) acc = fmaf(W[r * 4 * HID + k], src[k], acc);
        if (tid < 2 * HID) sh[r] = acc; else sc[r] = acc;
    }
    __syncthreads();
    for (int dir = 0; dir < 2; ++dir) {
        if (tid < G) {
            float acc = db[dir * G + tid] - dWih[dir * G + tid];   // input = -1.0
            for (int k = 0; k < HID; ++k)
                acc = fmaf(dWhh[(dir * G + tid) * HID + k], sh[dir * HID + k], acc);
            sz[tid] = acc;
        }
        __syncthreads();
        if (tid < HID) {
            float si = sigm(sz[tid]);
            float sf = sigm(sz[HID + tid]);
            float tg = tanh_(sz[2 * HID + tid]);
            float so = sigm(sz[3 * HID + tid]);
            float c2 = fmaf(sf, sc[dir * HID + tid], si * tg);
            dec[dir * HID + tid] = so * tanh_(c2);
        }
        __syncthreads();
    }
}

// ---------------------------------------------------------------------------
// Kernel 7: preds row 0 only
// ---------------------------------------------------------------------------
__global__ void k_row0(const float* __restrict__ dec, const float* __restrict__ outW,
                       const float* __restrict__ outb, float* __restrict__ preds)
{
    int n = blockIdx.x * blockDim.x + threadIdx.x;
    if (n >= VOCAB) return;
    float acc = outb[n];
    const float* w = outW + (size_t)n * 26;
    #pragma unroll
    for (int k = 0; k < 26; ++k) acc = fmaf(w[k], dec[k], acc);
    preds[n] = acc;
}

// ---------------------------------------------------------------------------
extern "C" void kernel_launch(void* const* d_in, const int* in_sizes, int n_in,
                              void* d_out, int out_size, void* d_ws, size_t ws_size,
                              hipStream_t stream)
{
    (void)in_sizes; (void)n_in; (void)out_size; (void)ws_size;

    const int*   x     = (const int*)d_in[0];
    const float* embW  = (const float*)d_in[1];
    const float* eWih0 = (const float*)d_in[2];
    const float* eWhh0 = (const float*)d_in[3];
    const float* eb0   = (const float*)d_in[4];
    const float* eWih1 = (const float*)d_in[5];
    const float* eWhh1 = (const float*)d_in[6];
    const float* eb1   = (const float*)d_in[7];
    const float* p1W   = (const float*)d_in[8];
    const float* p1b   = (const float*)d_in[9];
    const float* p2W   = (const float*)d_in[10];
    const float* p2b   = (const float*)d_in[11];
    const float* dWih  = (const float*)d_in[12];
    const float* dWhh  = (const float*)d_in[13];
    const float* db    = (const float*)d_in[14];
    const float* outW  = (const float*)d_in[15];
    const float* outb  = (const float*)d_in[16];

    float* ws    = (float*)d_ws;
    float* u0    = ws;                       // 2*L*64
    float* u1    = u0 + 2 * L * 64;          // 2*L*64
    float* out0p = u1 + 2 * L * 64;          // 2*L*64 (padded h store)
    float* dec   = out0p + 2 * L * 64;       // L*26
    float* fin_h = dec + L * 2 * HID;        // 52
    float* fin_c = fin_h + G;                // 52

    float* preds    = (float*)d_out;
    float* out_embs = preds + PRED_N;

    hipLaunchKernelGGL(k_emb_u0, dim3(L), dim3(128), 0, stream,
                       x, embW, eWih0, eb0, out_embs, u0);

    int restN = (L - 1) * 2 * HID;
    hipLaunchKernelGGL(k_rest, dim3((restN + 255) / 256), dim3(256), 0, stream, x, dWih, db, dec);

    hipLaunchKernelGGL(k_phase0, dim3(2 + NTILE), dim3(256), 0, stream,
                       u0, eWhh0, out0p, fin_h, fin_c,
                       dec, outW, outb, preds);

    hipLaunchKernelGGL(k_u1, dim3((L * 2 * 64 + 255) / 256), dim3(256), 0, stream,
                       out0p, eWih1, eb1, u1);

    hipLaunchKernelGGL(k_phase1, dim3(2), dim3(64), 0, stream,
                       u1, eWhh1, fin_h, fin_c);

    hipLaunchKernelGGL(k_final, dim3(1), dim3(64), 0, stream,
                       fin_h, fin_c, p1W, p1b, p2W, p2b, dWih, dWhh, db, dec);

    hipLaunchKernelGGL(k_row0, dim3((VOCAB + 255) / 256), dim3(256), 0, stream,
                       dec, outW, outb, preds);
}

// Round 9
// 576.220 us; speedup vs baseline: 1.5722x; 1.0609x over previous
//
#include <hip/hip_runtime.h>
#include <hip/hip_bf16.h>
#include <cstdint>
#include <cstddef>

#define L      2048
#define IN_DIM 256
#define HID    13
#define G      52            // 4*HID
#define VOCAB  50257
#define PRED_N ((size_t)L * VOOCAB)
#define L2E    1.4426950408889634f
#define INV2L2E 0.34657359027997264f
#define NTX    99            // x-tiles of 512 cols (99*512 >= 50257)
#define NTY    16            // y-tiles of 128 rows
#define NTILE  (NTX * NTY)   // 1584
#define GB     254           // GEMM blocks (grid = 2 + GB = 256 = #CUs)
#undef PRED_N
#define PRED_N ((size_t)L * VOCAB)

static __device__ __forceinline__ float fexp2(float x) { return __builtin_amdgcn_exp2f(x); }
static __device__ __forceinline__ float frcp(float x) { return __builtin_amdgcn_rcpf(x); }
static __device__ __forceinline__ float sigm(float z) { return 1.f - frcp(fexp2(z * L2E) + 1.f); }
static __device__ __forceinline__ float tanh_(float z) { return 1.f - 2.f * frcp(fexp2(z * (2.f * L2E)) + 1.f); }
static __device__ __forceinline__ float bcast(float v, int l) {
    return __int_as_float(__builtin_amdgcn_readlane(__float_as_int(v), l));
}

// ---------------------------------------------------------------------------
// Kernel 1: embedding gather (-> d_out embs section) + u0 = msc*(Wih0@emb+b0)
// + dec row t (zero-state decoder cell, t>=1). grid = L blocks, 160 threads.
// ---------------------------------------------------------------------------
__global__ void __launch_bounds__(160) k_emb_u0(
    const int* __restrict__ x, const float* __restrict__ embW,
    const float* __restrict__ Wih0, const float* __restrict__ b0,
    const float* __restrict__ dWih, const float* __restrict__ db,
    float* __restrict__ out_embs, float* __restrict__ u0, float* __restrict__ dec)
{
    __shared__ float se[IN_DIM];
    int t = blockIdx.x;
    int tid = threadIdx.x;            // 160
    if (tid < 128) {
        int rowx = x[t];
        float2 e = ((const float2*)(embW + (size_t)rowx * IN_DIM))[tid];
        se[2 * tid]     = e.x;
        se[2 * tid + 1] = e.y;
        ((float2*)(out_embs + (size_t)t * IN_DIM))[tid] = e;
    }
    __syncthreads();
    if (tid < 2 * G) {
        int dirg = tid / G, g = tid % G;
        int gate = g / HID, row = g % HID;
        float msc = (gate == 2) ? 2.f * L2E : L2E;
        float acc = b0[dirg * G + g];
        const float* w = Wih0 + (size_t)(dirg * G + g) * IN_DIM;
        #pragma unroll 8
        for (int k = 0; k < IN_DIM; ++k)
            acc = fmaf(w[k], se[k], acc);
        u0[((size_t)dirg * L + t) * 64 + gate * 16 + row] = msc * acc;
    } else if (tid < 128) {
        int p = tid - 2 * G;          // 0..23 -> zero the 2*12 pad slots
        int dirp = p / 12, pp = p % 12;
        int gate = pp / 3, row = HID + pp % 3;
        u0[((size_t)dirp * L + t) * 64 + gate * 16 + row] = 0.f;
    } else if (tid < 128 + 2 * HID && t >= 1) {
        // dec row t (zero-state cell; c=0 so f-gate drops out)
        int j = tid - 128;            // 0..25
        int dir = j / HID, jj = j % HID;
        float v = (float)x[t - 1];
        int base = dir * G;
        float zi = fmaf(dWih[base + jj],           v, db[base + jj]);
        float zg = fmaf(dWih[base + 2 * HID + jj], v, db[base + 2 * HID + jj]);
        float zo = fmaf(dWih[base + 3 * HID + jj], v, db[base + 3 * HID + jj]);
        float c2 = sigm(zi) * tanh_(zg);
        dec[(size_t)t * (2 * HID) + j] = sigm(zo) * tanh_(c2);
    }
}

// ---------------------------------------------------------------------------
// Recurrence body: per-lane cndmask selects (m16/m32 are LANE-VARYING).
// Template only on DOUT (wave-uniform). c tracked in 2*L2E units.
// ---------------------------------------------------------------------------
template<bool DOUT>
static __device__ __forceinline__ void chain_run(
    const float* __restrict__ ub, int pstep,
    const float* __restrict__ whh, float kcv, float onev,
    bool m16, bool m32,
    float* __restrict__ outp,
    float& hout, float& cout)
{
    float h = 0.f, c = 0.f;      // c in 2*L2E units
    float cur[8], nxt[8];
    #pragma unroll
    for (int k = 0; k < 8; ++k) cur[k] = ub[k * pstep];
    #pragma unroll
    for (int k = 0; k < 8; ++k) nxt[k] = cur[k];
    const float* upf = ub + (ptrdiff_t)8 * pstep;

    for (int tcb = 0; tcb < L; tcb += 8) {
        if (tcb + 8 < L) {
            #pragma unroll
            for (int k = 0; k < 8; ++k) nxt[k] = upf[k * pstep];
            upf += (ptrdiff_t)8 * pstep;
        }
        #pragma unroll
        for (int k = 0; k < 8; ++k) {
            float h0 = bcast(h, 0), h1 = bcast(h, 1), h2 = bcast(h, 2), h3 = bcast(h, 3);
            float h4 = bcast(h, 4), h5 = bcast(h, 5), h6 = bcast(h, 6), h7 = bcast(h, 7);
            float h8 = bcast(h, 8), h9 = bcast(h, 9), h10 = bcast(h, 10), h11 = bcast(h, 11);
            float h12 = bcast(h, 12);
            float A = fmaf(whh[0], h0, cur[k]);
            float B = whh[1] * h1;
            float C = whh[2] * h2;
            float D = whh[3] * h3;
            A = fmaf(whh[4], h4, A);   B = fmaf(whh[5], h5, B);
            C = fmaf(whh[6], h6, C);   D = fmaf(whh[7], h7, D);
            A = fmaf(whh[8], h8, A);   B = fmaf(whh[9], h9, B);
            C = fmaf(whh[10], h10, C); D = fmaf(whh[11], h11, D);
            A = fmaf(whh[12], h12, A);
            float z = (A + B) + (C + D);              // pre-scaled
            float act = fmaf(-kcv, frcp(fexp2(z) + 1.f), onev);
            float pa = act, pb = act;
            asm("s_nop 1\n\tv_permlane16_swap_b32 %0, %1" : "+v"(pa), "+v"(pb));
            float sf = m16 ? pa : pb;                 // act[lane^16]
            float qa = act, qb = act;
            asm("s_nop 1\n\tv_permlane32_swap_b32 %0, %1" : "+v"(qa), "+v"(qb));
            float tg = m32 ? qa : qb;                 // act[lane^32]
            float ra = tg, rb = tg;
            asm("s_nop 1\n\tv_permlane16_swap_b32 %0, %1" : "+v"(ra), "+v"(rb));
            float so = m16 ? ra : rb;                 // act[lane^48]
            float c2 = fmaf(sf, c, act * tg);         // 2*L2E units (grp0 valid)
            float th = fmaf(-2.f, frcp(fexp2(c2) + 1.f), 1.f);
            h = so * th;
            c = c2;
            if (DOUT) { *outp = h; outp += pstep; }
        }
        #pragma unroll
        for (int k = 0; k < 8; ++k) cur[k] = nxt[k];
    }
    hout = h; cout = c;
}

static __device__ __forceinline__ void chain_setup_and_run(
    const float* __restrict__ u, const float* __restrict__ Whh,
    float* __restrict__ out0p, float* __restrict__ finh, float* __restrict__ finc,
    int chain_base, int do_out0, int dir, int lane)
{
    int lg16 = lane & 15, gate = lane >> 4;
    int rsrc = gate * HID + (lg16 < HID ? lg16 : HID - 1);   // clamp
    float kcv, onev;
    if (gate == 2)      { kcv = 2.f;        onev = 1.f; }         // g: tanh
    else if (gate == 0) { kcv = 2.f * L2E;  onev = 2.f * L2E; }   // i: prescaled sigmoid
    else                { kcv = 1.f;        onev = 1.f; }         // f,o: sigmoid
    float msc = (gate == 2) ? 2.f * L2E : L2E;
    float whh[HID];
    #pragma unroll
    for (int k = 0; k < HID; ++k) whh[k] = msc * Whh[(dir * G + rsrc) * HID + k];

    // runtime detection of permlane swap result placement (PER-LANE masks)
    int ia = lane, ib = lane;
    asm("s_nop 1\n\tv_permlane16_swap_b32 %0, %1" : "+v"(ia), "+v"(ib));
    bool m16 = (ia == (lane ^ 16));
    int ja = lane, jb = lane;
    asm("s_nop 1\n\tv_permlane32_swap_b32 %0, %1" : "+v"(ja), "+v"(jb));
    bool m32 = (ja == (lane ^ 32));

    const float* ub = u + (size_t)dir * L * 64 + (dir ? (size_t)(L - 1) * 64 : 0) + lane;
    int pstep = dir ? -64 : 64;
    float* outp = out0p + ((size_t)dir * L + (dir ? L - 1 : 0)) * 64 + lane;

    float h, c;
    if (do_out0) chain_run<true >(ub, pstep, whh, kcv, onev, m16, m32, outp, h, c);
    else         chain_run<false>(ub, pstep, whh, kcv, onev, m16, m32, outp, h, c);

    if (lane < HID) {
        finh[(chain_base + dir) * HID + lane] = h;
        finc[(chain_base + dir) * HID + lane] = c * INV2L2E;
    }
}

// ---------------------------------------------------------------------------
// Kernel 3 (phase 0): grid = 256 blocks (one per CU). Blocks 0,1 = layer-0
// chains (solo on their CU). Blocks 2..255 = GEMM workers, each looping over
// a balanced chunk of the 1584 output tiles (rows 1..L-1).
// ---------------------------------------------------------------------------
__global__ void __launch_bounds__(256) k_phase0(
    const float* __restrict__ u, const float* __restrict__ Whh,
    float* __restrict__ out0p, float* __restrict__ finh, float* __restrict__ finc,
    const float* __restrict__ dec, const float* __restrict__ outW,
    const float* __restrict__ outb, float* __restrict__ preds)
{
    __shared__ float sd[128][28];
    int bid = blockIdx.x;
    int tid = threadIdx.x;
    if (bid >= 2) {
        // ---- GEMM worker: chunk of tiles ----
        __builtin_amdgcn_s_setprio(0);
        int b = bid - 2;                       // 0..GB-1
        const int q = NTILE / GB, r = NTILE % GB;
        int start = b * q + (b < r ? b : r);
        int cnt   = q + (b < r ? 1 : 0);
        for (int tt = 0; tt < cnt; ++tt) {
            int tile = start + tt;
            int ix = tile % NTX, iy = tile / NTX;
            int nbase = ix * 512, i0 = iy * 128;
            __syncthreads();                   // protect sd reuse
            for (int li = tid; li < 128 * 26; li += 256) {
                int rr_ = li / 26, cc = li % 26;
                sd[rr_][cc] = dec[(size_t)(i0 + rr_) * 26 + cc];
            }
            __syncthreads();
            int n0 = nbase + tid, n1 = nbase + 256 + tid;
            bool a0 = n0 < VOCAB, a1 = n1 < VOCAB;
            float w0[26], w1[26], b0v = 0.f, b1v = 0.f;
            #pragma unroll
            for (int k = 0; k < 26; ++k) { w0[k] = 0.f; w1[k] = 0.f; }
            if (a0) { const float* w = outW + (size_t)n0 * 26;
                #pragma unroll
                for (int k = 0; k < 26; ++k) w0[k] = w[k];
                b0v = outb[n0]; }
            if (a1) { const float* w = outW + (size_t)n1 * 26;
                #pragma unroll
                for (int k = 0; k < 26; ++k) w1[k] = w[k];
                b1v = outb[n1]; }
            for (int i = 0; i < 128; ++i) {
                int grow = i0 + i;
                float acc0 = b0v, acc1 = b1v;
                const float* dr = sd[i];
                #pragma unroll
                for (int k = 0; k < 26; ++k) {
                    float d = dr[k];
                    acc0 = fmaf(d, w0[k], acc0);
                    acc1 = fmaf(d, w1[k], acc1);
                }
                if (grow != 0) {               // row 0 written later by k_row0
                    size_t rb = (size_t)grow * VOCAB;
                    if (a0) preds[rb + n0] = acc0;
                    if (a1) preds[rb + n1] = acc1;
                }
            }
        }
        return;
    }
    if (tid >= 64) return;
    __builtin_amdgcn_s_setprio(3);
    chain_setup_and_run(u, Whh, out0p, finh, finc, 0, 1, bid, tid);
}

// ---------------------------------------------------------------------------
// Kernel 5 (phase 1): chain-only, 2 blocks x 64
// ---------------------------------------------------------------------------
__global__ void __launch_bounds__(64) k_phase1(
    const float* __restrict__ u, const float* __restrict__ Whh,
    float* __restrict__ finh, float* __restrict__ finc)
{
    chain_setup_and_run(u, Whh, (float*)nullptr, finh, finc, 2, 0, blockIdx.x, threadIdx.x);
}

// ---------------------------------------------------------------------------
// Kernel 4: u1 = msc*(Wih1 @ out0 + b1), out0p padded [dir][L][64]
// ---------------------------------------------------------------------------
__global__ void k_u1(const float* __restrict__ out0p, const float* __restrict__ Wih1,
                     const float* __restrict__ b1, float* __restrict__ u1)
{
    int idx = blockIdx.x * blockDim.x + threadIdx.x;
    if (idx >= L * 2 * 64) return;
    int t    = idx >> 7;
    int remv = idx & 127;
    int d1   = remv >> 6;
    int lane = remv & 63;
    int gate = lane >> 4, row = lane & 15;
    size_t oidx = ((size_t)d1 * L + t) * 64 + lane;
    if (row >= HID) { u1[oidx] = 0.f; return; }
    int g = gate * HID + row;
    float msc = (gate == 2) ? 2.f * L2E : L2E;
    float acc = b1[d1 * G + g];
    const float* w = Wih1 + (size_t)(d1 * G + g) * (2 * HID);
    const float* o0 = out0p + (size_t)t * 64;            // dir0 h at lanes 0..12
    const float* o1 = out0p + ((size_t)L + t) * 64;      // dir1 h at lanes 0..12
    #pragma unroll
    for (int k = 0; k < HID; ++k)
        acc = fmaf(w[k], o0[k], acc);
    #pragma unroll
    for (int k = 0; k < HID; ++k)
        acc = fmaf(w[HID + k], o1[k], acc);
    u1[oidx] = msc * acc;
}

// ---------------------------------------------------------------------------
// Kernel 6: projections + decoder step 0 (with state) -> dec[0][0:26]
// ---------------------------------------------------------------------------
__global__ void __launch_bounds__(64) k_final(const float* __restrict__ fin_h, const float* __restrict__ fin_c,
                                              const float* __restrict__ p1W, const float* __restrict__ p1b,
                                              const float* __restrict__ p2W, const float* __restrict__ p2b,
                                              const float* __restrict__ dWih, const float* __restrict__ dWhh,
                                              const float* __restrict__ db, float* __restrict__ dec)
{
    __shared__ float sh[2 * HID], sc[2 * HID], sz[G];
    int tid = threadIdx.x;
    if (tid < 4 * HID) {
        int r = tid < 2 * HID ? tid : tid - 2 * HID;
        const float* W   = tid < 2 * HID ? p1W : p2W;
        const float* src = tid < 2 * HID ? fin_h : fin_c;
        float acc = tid < 2 * HID ? p1b[r] : p2b[r];
        for (int k = 0; k < 4 * HID; ++k) acc = fmaf(W[r * 4 * HID + k], src[k], acc);
        if (tid < 2 * HID) sh[r] = acc; else sc[r] = acc;
    }
    __syncthreads();
    for (int dir = 0; dir < 2; ++dir) {
        if (tid < G) {
            float acc = db[dir * G + tid] - dWih[dir * G + tid];   // input = -1.0
            for (int k = 0; k < HID; ++k)
                acc = fmaf(dWhh[(dir * G + tid) * HID + k], sh[dir * HID + k], acc);
            sz[tid] = acc;
        }
        __syncthreads();
        if (tid < HID) {
            float si = sigm(sz[tid]);
            float sf = sigm(sz[HID + tid]);
            float tg = tanh_(sz[2 * HID + tid]);
            float so = sigm(sz[3 * HID + tid]);
            float c2 = fmaf(sf, sc[dir * HID + tid], si * tg);
            dec[dir * HID + tid] = so * tanh_(c2);
        }
        __syncthreads();
    }
}

// ---------------------------------------------------------------------------
// Kernel 7: preds row 0 only
// ---------------------------------------------------------------------------
__global__ void k_row0(const float* __restrict__ dec, const float* __restrict__ outW,
                       const float* __restrict__ outb, float* __restrict__ preds)
{
    int n = blockIdx.x * blockDim.x + threadIdx.x;
    if (n >= VOCAB) return;
    float acc = outb[n];
    const float* w = outW + (size_t)n * 26;
    #pragma unroll
    for (int k = 0; k < 26; ++k) acc = fmaf(w[k], dec[k], acc);
    preds[n] = acc;
}

// ---------------------------------------------------------------------------
extern "C" void kernel_launch(void* const* d_in, const int* in_sizes, int n_in,
                              void* d_out, int out_size, void* d_ws, size_t ws_size,
                              hipStream_t stream)
{
    (void)in_sizes; (void)n_in; (void)out_size; (void)ws_size;

    const int*   x     = (const int*)d_in[0];
    const float* embW  = (const float*)d_in[1];
    const float* eWih0 = (const float*)d_in[2];
    const float* eWhh0 = (const float*)d_in[3];
    const float* eb0   = (const float*)d_in[4];
    const float* eWih1 = (const float*)d_in[5];
    const float* eWhh1 = (const float*)d_in[6];
    const float* eb1   = (const float*)d_in[7];
    const float* p1W   = (const float*)d_in[8];
    const float* p1b   = (const float*)d_in[9];
    const float* p2W   = (const float*)d_in[10];
    const float* p2b   = (const float*)d_in[11];
    const float* dWih  = (const float*)d_in[12];
    const float* dWhh  = (const float*)d_in[13];
    const float* db    = (const float*)d_in[14];
    const float* outW  = (const float*)d_in[15];
    const float* outb  = (const float*)d_in[16];

    float* ws    = (float*)d_ws;
    float* u0    = ws;                       // 2*L*64
    float* u1    = u0 + 2 * L * 64;          // 2*L*64
    float* out0p = u1 + 2 * L * 64;          // 2*L*64 (padded h store)
    float* dec   = out0p + 2 * L * 64;       // L*26
    float* fin_h = dec + L * 2 * HID;        // 52
    float* fin_c = fin_h + G;                // 52

    float* preds    = (float*)d_out;
    float* out_embs = preds + PRED_N;

    hipLaunchKernelGGL(k_emb_u0, dim3(L), dim3(160), 0, stream,
                       x, embW, eWih0, eb0, dWih, db, out_embs, u0, dec);

    hipLaunchKernelGGL(k_phase0, dim3(2 + GB), dim3(256), 0, stream,
                       u0, eWhh0, out0p, fin_h, fin_c,
                       dec, outW, outb, preds);

    hipLaunchKernelGGL(k_u1, dim3((L * 2 * 64 + 255) / 256), dim3(256), 0, stream,
                       out0p, eWih1, eb1, u1);

    hipLaunchKernelGGL(k_phase1, dim3(2), dim3(64), 0, stream,
                       u1, eWhh1, fin_h, fin_c);

    hipLaunchKernelGGL(k_final, dim3(1), dim3(64), 0, stream,
                       fin_h, fin_c, p1W, p1b, p2W, p2b, dWih, dWhh, db, dec);

    hipLaunchKernelGGL(k_row0, dim3((VOCAB + 255) / 256), dim3(256), 0, stream,
                       dec, outW, outb, preds);
}